// Round 15
// baseline (667.188 us; speedup 1.0000x reference)
//
#include <hip/hip_runtime.h>
#include <hip/hip_bf16.h>
#include <math.h>

// Shapes: grd (N=64,C=64,24,24), sat (M=64,C=64,64,64); crop sat[:,:,12:52,12:52] (40x40)
// corr (64,64,17,17); out: [0,4096) similarity f32, [4096,40960) sat_f (64,24,24) f32.
//
// Round-15: restore occupancy (12 waves/CU) at ratio 0.83 via LDS diet: c-chunks of
// 16 (satW 23KB + Bl 4KB), satT relaid [m][cc][pix][16c] for linear staging, grid
// 768 (12 i-slices x 2 rows), launch_bounds(256,3). 10 real p-tiles (wave-uniform
// T=3/T=2 branch) cuts ghost MFMAs. Single bf16-product corr (near-tie flips only;
// sim err <2e-4); (63,63) made exact via fp32 rescore for sat_f.

typedef float f32x16 __attribute__((ext_vector_type(16)));
typedef short short8 __attribute__((ext_vector_type(8)));

// ws layout (float words)
#define SATT_H 0u          // bf16 [m][4 cc][1600 pix][16 c] = 3,276,800 f
#define GRDT_H 3276800u    // bf16 [ij=576][n=64][c=64] = 1,179,648 f
#define CORR_O 4456448u    // f32 [m][304][64] = 1,245,184 f
#define WIN2_O 5701632u    // f32 [m][289] -> 18,496 f
#define GN2_O  5720128u    // f32 [64]
#define IDX_O  5720192u    // int [4096] (1024 f)
#define CEX_O  5721216u    // f32 [289]

// LDS swizzle for 32-B rows: XOR chunk bits (6:4) with bits (9:7) (= row>>2).
// Involution, applied identically on write and read; balances any 32-lane b128
// fragment read across all 8 bank groups.
#define SWZ(off) ((off) ^ ((((off) >> 7) & 7) << 4))

// ---------- T1: satT bf16 [m][cc][pix][16c]. grid 2560 = (m, r); block 256 ----------
__global__ __launch_bounds__(256) void make_satT(const float* __restrict__ sat,
                                                 __hip_bfloat16* __restrict__ sth) {
    __shared__ __hip_bfloat16 th[40 * 66];
    int m = blockIdx.x / 40, r = blockIdx.x % 40;
    int tid = threadIdx.x;
    const float* base = sat + (size_t)m * 262144 + (12 + r) * 64 + 12;
    for (int k = 0; k < 10; k++) {
        int idx = tid + 256 * k;          // 2560 = 64c * 40w
        int c = idx / 40, w2 = idx % 40;
        th[w2 * 66 + c] = __float2bfloat16(base[c * 4096 + w2]);
    }
    __syncthreads();
    __hip_bfloat16* dh = sth + (size_t)m * 102400;
    for (int k = 0; k < 10; k++) {
        int idx = tid + 256 * k;          // idx = w*64 + c
        int w2 = idx >> 6, c = idx & 63;
        dh[(c >> 4) * 25600 + (r * 40 + w2) * 16 + (c & 15)] = th[w2 * 66 + c];
    }
}

// ---------- T2: grdT bf16 [ij][n][c] + gn2. grid 128 = (n, c-half); block 256 ----------
__global__ __launch_bounds__(256) void make_grdT(const float* __restrict__ grd,
                                                 __hip_bfloat16* __restrict__ gth,
                                                 float* __restrict__ gn2) {
    __shared__ __hip_bfloat16 t[32 * 577];
    __shared__ float red[4];
    int bid = blockIdx.x;
    int n = bid >> 1, ch = bid & 1;
    int tid = threadIdx.x;
    const float* src = grd + (size_t)n * 36864 + ch * 32 * 576;
    float s = 0.0f;
    for (int k = 0; k < 72; k++) {
        int idx = tid + 256 * k;          // idx = cl*576 + ij
        int cl = idx / 576, ij = idx % 576;
        float v = src[idx];
        s += v * v;
        t[cl * 577 + ij] = __float2bfloat16(v);
    }
    for (int off = 32; off; off >>= 1) s += __shfl_down(s, off);
    if ((tid & 63) == 0) red[tid >> 6] = s;
    __syncthreads();
    if (tid == 0) atomicAdd(&gn2[n], red[0] + red[1] + red[2] + red[3]);
    for (int k = 0; k < 72; k++) {
        int idx = tid + 256 * k;          // idx = ij*32 + cl
        int ij = idx >> 5, cl = idx & 31;
        gth[(size_t)ij * 4096 + n * 64 + ch * 32 + cl] = t[cl * 577 + ij];
    }
}

// ---------- N1: window norms^2 from satT (bf16; rel err ~2e-5). grid 64 (m) ----------
__global__ __launch_bounds__(256) void make_win2(const __hip_bfloat16* __restrict__ sth,
                                                 float* __restrict__ win2) {
    __shared__ float S2[40][41];
    __shared__ float RS[40][18];
    int m = blockIdx.x, tid = threadIdx.x;
    const __hip_bfloat16* base = sth + (size_t)m * 102400;
    for (int k = 0; k < 7; k++) {
        int pix = tid + 256 * k;
        if (pix < 1600) {
            float s = 0.0f;
            for (int cc = 0; cc < 4; cc++) {
                const __hip_bfloat16* p = base + cc * 25600 + pix * 16;
                for (int cl = 0; cl < 16; cl++) {
                    float v = __bfloat162float(p[cl]);
                    s += v * v;
                }
            }
            S2[pix / 40][pix % 40] = s;
        }
    }
    __syncthreads();
    for (int k = 0; k < 3; k++) {
        int idx = tid + 256 * k;
        if (idx < 680) {
            int r = idx / 17, x = idx % 17;
            float s = 0.0f;
            for (int j = 0; j < 24; j++) s += S2[r][x + j];
            RS[r][x] = s;
        }
    }
    __syncthreads();
    for (int k = 0; k < 2; k++) {
        int idx = tid + 256 * k;
        if (idx < 289) {
            int y = idx / 17, x = idx % 17;
            float s = 0.0f;
            for (int i2 = 0; i2 < 24; i2++) s += RS[y + i2][x];
            win2[m * 289 + idx] = s;
        }
    }
}

// ---------- K1: MFMA corr (32x32x16, P3N2/P2N2 split). grid 768; block 256 ----------
// 12 i-slices of 2 rows; ijl = il*24+j (48 iters) x 4 c-chunks of 16. satW = 720 pix
// x 16 c (18 window rows x 40 cols), staged as a LINEAR 23KB copy from the relaid
// satT. Waves 0-1: p-tiles {w, w+4, w+8}; waves 2-3: {w, w+4} (10 real tiles, tile 9
// tail-clamped; stores guarded). Both n-tiles per wave -> each A-read feeds 2 MFMAs.
// Bl (2KB/ij) double-buffered with reg prefetch by threads<128.
__global__ __launch_bounds__(256, 3) void corr_mfma(const __hip_bfloat16* __restrict__ sth,
                                                    const __hip_bfloat16* __restrict__ gth,
                                                    float* __restrict__ corr) {
    __shared__ __align__(16) __hip_bfloat16 satW[720 * 16];   // 23,040 B
    __shared__ __align__(16) __hip_bfloat16 Bl[2][64 * 16];   // 2 x 2,048 B

    int bid = blockIdx.x;
    int xcd = bid & 7, slot = bid >> 3;             // 96 slots per XCD
    int m = xcd * 8 + slot / 12, iq = slot % 12;    // 12 i-slices of 2 rows per m
    int tid = threadIdx.x;
    int w = tid >> 6, l = tid & 63;
    int ln31 = l & 31, h = l >> 5;

    int rowbase[3];
#pragma unroll
    for (int t = 0; t < 3; t++) {
        int p = (w + 4 * t) * 32 + ln31;
        if (p > 288) p = 288;                       // tail rows clamp to a valid pixel
        rowbase[t] = (p / 17) * 40 + (p % 17);
    }
    f32x16 acc[3][2];
#pragma unroll
    for (int t = 0; t < 3; t++) {
        acc[t][0] = (f32x16)0.0f;
        acc[t][1] = (f32x16)0.0f;
    }

    // satT source for this (m, iq, cc): linear 23,040-B window starting at
    // pix = 2*iq*40 within the [cc][1600 pix][16 c] plane.
    const __hip_bfloat16* satm = sth + (size_t)m * 102400 + iq * 1280;
    // B: gth[ijg = iq*48 + ijl][n*64 + cc*16 + ...]; threads<128: n=tid>>1, seg=tid&1.
    size_t gb = (size_t)(iq * 48) * 4096 + (tid >> 1) * 64 + (tid & 1) * 8;
    int bdst = SWZ(tid * 16);                       // valid for tid<128
    int bro[2];
#pragma unroll
    for (int nt = 0; nt < 2; nt++)
        bro[nt] = SWZ((nt * 32 + ln31) * 32 + h * 16);

#pragma unroll
    for (int cc = 0; cc < 4; cc++) {
        const __hip_bfloat16* satb = satm + cc * 25600;
        __syncthreads();                            // prior satW/Bl reads done
        // stage satW: 1440 linear 16-B slots
#pragma unroll
        for (int k2 = 0; k2 < 6; k2++) {
            int s = tid + 256 * k2;
            if (s < 1440) {
                float4 v = *(const float4*)(satb + s * 8);
                *(float4*)((char*)satW + SWZ(s * 16)) = v;
            }
        }
        float4 vnext;
        if (tid < 128) {
            float4 v0 = *(const float4*)(gth + gb + cc * 16);
            *(float4*)((char*)&Bl[0][0] + bdst) = v0;
            vnext = *(const float4*)(gth + gb + 4096 + cc * 16);
        }
        __syncthreads();

        for (int ijl = 0; ijl < 48; ijl++) {
            int buf = ijl & 1;
            if (tid < 128 && ijl + 1 < 48) {
                *(float4*)((char*)&Bl[buf ^ 1][0] + bdst) = vnext;
                if (ijl + 2 < 48)
                    vnext = *(const float4*)(gth + gb + (size_t)(ijl + 2) * 4096 + cc * 16);
            }
            int pixoff = ijl + ((ijl >= 24) ? 16 : 0);   // il*40 + j

            short8 bf0 = *(const short8*)((const char*)&Bl[buf][0] + bro[0]);
            short8 bf1 = *(const short8*)((const char*)&Bl[buf][0] + bro[1]);
            if (w < 2) {
#pragma unroll
                for (int t = 0; t < 3; t++) {
                    int ao = (rowbase[t] + pixoff) * 32 + h * 16;
                    short8 af = *(const short8*)((const char*)satW + SWZ(ao));
                    acc[t][0] = __builtin_amdgcn_mfma_f32_32x32x16_bf16(af, bf0, acc[t][0], 0, 0, 0);
                    acc[t][1] = __builtin_amdgcn_mfma_f32_32x32x16_bf16(af, bf1, acc[t][1], 0, 0, 0);
                }
            } else {
#pragma unroll
                for (int t = 0; t < 2; t++) {
                    int ao = (rowbase[t] + pixoff) * 32 + h * 16;
                    short8 af = *(const short8*)((const char*)satW + SWZ(ao));
                    acc[t][0] = __builtin_amdgcn_mfma_f32_32x32x16_bf16(af, bf0, acc[t][0], 0, 0, 0);
                    acc[t][1] = __builtin_amdgcn_mfma_f32_32x32x16_bf16(af, bf1, acc[t][1], 0, 0, 0);
                }
            }
            __syncthreads();
        }
    }

    int T = (w < 2) ? 3 : 2;
#pragma unroll
    for (int t = 0; t < 3; t++) {
        if (t >= T) break;
        int tile = w + 4 * t;
#pragma unroll
        for (int nt = 0; nt < 2; nt++)
#pragma unroll
            for (int q = 0; q < 16; q++) {
                int prow = tile * 32 + (q & 3) + 8 * (q >> 2) + 4 * h;
                if (prow < 289)
                    atomicAdd(&corr[((size_t)m * 304 + prow) * 64 + nt * 32 + ln31],
                              acc[t][nt][q]);
            }
    }
}

// ---------- K2: argmax + similarity. grid 4096 = (m,n); block 64 ----------
__global__ __launch_bounds__(64) void argsim(const float* __restrict__ corr,
                                             const float* __restrict__ win2,
                                             const float* __restrict__ gn2,
                                             float* __restrict__ out,
                                             int* __restrict__ idxb) {
    int b = blockIdx.x, m = b >> 6, n = b & 63, lane = threadIdx.x;
    float bv = -3.0e38f;
    int bi = 1 << 30;
    for (int k = 0; k < 5; k++) {
        int p = lane + 64 * k;
        if (p < 289) {
            float v = corr[((size_t)m * 304 + p) * 64 + n];
            if (v > bv) { bv = v; bi = p; }   // ascending p: strict > = first occurrence
        }
    }
    for (int off = 32; off; off >>= 1) {
        float ov = __shfl_down(bv, off);
        int oi = __shfl_down(bi, off);
        if (ov > bv || (ov == bv && oi < bi)) { bv = ov; bi = oi; }
    }
    if (lane == 0) {
        float np = sqrtf(win2[m * 289 + bi]);
        float ng = sqrtf(gn2[n]);
        out[b] = bv / (fmaxf(np, 1e-12f) * fmaxf(ng, 1e-12f));
        idxb[b] = bi;
    }
}

// ---------- K3a: exact fp32 corr for (m,n)=(63,63). grid 289; block 256 ----------
__global__ __launch_bounds__(256) void exact63(const float* __restrict__ sat,
                                               const float* __restrict__ grd,
                                               float* __restrict__ correx) {
    int p = blockIdx.x;
    int hy = p / 17, wx = p % 17;
    int tid = threadIdx.x;
    const float* satm = sat + (size_t)63 * 262144;
    const float* grdn = grd + (size_t)63 * 36864;
    float dot = 0.0f;
    for (int e = tid; e < 36864; e += 256) {
        int c = e / 576, rem = e - c * 576;
        int i = rem / 24, j = rem - i * 24;
        dot += satm[c * 4096 + (12 + hy + i) * 64 + 12 + wx + j] * grdn[e];
    }
    for (int off = 32; off; off >>= 1) dot += __shfl_down(dot, off);
    __shared__ float red[4];
    if ((tid & 63) == 0) red[tid >> 6] = dot;
    __syncthreads();
    if (tid == 0) correx[p] = red[0] + red[1] + red[2] + red[3];
}

// ---------- K3b: fix (63,63) from exact values. grid 1; block 64 ----------
__global__ __launch_bounds__(64) void fix63(const float* __restrict__ correx,
                                            const float* __restrict__ win2,
                                            const float* __restrict__ gn2,
                                            float* __restrict__ out,
                                            int* __restrict__ idxb) {
    int lane = threadIdx.x;
    float bv = -3.0e38f;
    int bi = 1 << 30;
    for (int k = 0; k < 5; k++) {
        int p = lane + 64 * k;
        if (p < 289) {
            float v = correx[p];
            if (v > bv) { bv = v; bi = p; }
        }
    }
    for (int off = 32; off; off >>= 1) {
        float ov = __shfl_down(bv, off);
        int oi = __shfl_down(bi, off);
        if (ov > bv || (ov == bv && oi < bi)) { bv = ov; bi = oi; }
    }
    if (lane == 0) {
        out[4095] = bv / (fmaxf(sqrtf(win2[63 * 289 + bi]), 1e-12f) *
                          fmaxf(sqrtf(gn2[63]), 1e-12f));
        idxb[4095] = bi;
    }
}

// ---------- K4: winning patch for (63,63). grid 144; block 256 ----------
__global__ __launch_bounds__(256) void copy_patch(const float* __restrict__ sat,
                                                  const int* __restrict__ idxb,
                                                  float* __restrict__ out) {
    int fidx = idxb[4095];
    int hy = fidx / 17, wx = fidx % 17;
    int e = blockIdx.x * 256 + threadIdx.x;   // < 36864
    int c = e / 576;
    int rem = e - c * 576;
    int rr = rem / 24, col = rem - rr * 24;
    out[4096 + e] = sat[(size_t)(63 * 64 + c) * 4096 + (12 + hy + rr) * 64 + 12 + wx + col];
}

extern "C" void kernel_launch(void* const* d_in, const int* in_sizes, int n_in,
                              void* d_out, int out_size, void* d_ws, size_t ws_size,
                              hipStream_t stream) {
    const float* grd = (const float*)d_in[0];
    const float* sat = (const float*)d_in[1];
    float* out = (float*)d_out;

    float* wsf = (float*)d_ws;
    __hip_bfloat16* sth = (__hip_bfloat16*)(wsf + SATT_H);
    __hip_bfloat16* gth = (__hip_bfloat16*)(wsf + GRDT_H);
    float* corr = wsf + CORR_O;
    float* win2 = wsf + WIN2_O;
    float* gn2  = wsf + GN2_O;
    int*   idxb = (int*)(wsf + IDX_O);
    float* cex  = wsf + CEX_O;

    // one memset covers corr + win2 + gn2 (contiguous): 1,263,744 floats
    hipMemsetAsync(corr, 0, (size_t)1263744 * sizeof(float), stream);
    make_satT<<<2560, 256, 0, stream>>>(sat, sth);
    make_grdT<<<128, 256, 0, stream>>>(grd, gth, gn2);
    make_win2<<<64, 256, 0, stream>>>(sth, win2);
    corr_mfma<<<768, 256, 0, stream>>>(sth, gth, corr);
    argsim<<<4096, 64, 0, stream>>>(corr, win2, gn2, out, idxb);
    exact63<<<289, 256, 0, stream>>>(sat, grd, cex);
    fix63<<<1, 64, 0, stream>>>(cex, win2, gn2, out, idxb);
    copy_patch<<<144, 256, 0, stream>>>(sat, idxb, out);
}

// Round 16
// 192.808 us; speedup vs baseline: 3.4604x; 3.4604x over previous
//
#include <hip/hip_runtime.h>
#include <hip/hip_bf16.h>
#include <math.h>

// Shapes: grd (N=64,C=64,24,24), sat (M=64,C=64,64,64); crop sat[:,:,12:52,12:52] (40x40)
// corr (64,64,17,17); out: [0,4096) similarity f32, [4096,40960) sat_f (64,24,24) f32.
//
// Round-16: round-15 aux (fast, ~50us) + corr rebuilt on cc=16 chunks: all-linear
// LDS (32-B rows make fragment reads naturally contiguous -> no swizzle), grdT
// relaid [cc][ij][n][16c] for coalesced B staging, G=6 group-staged double-buffered
// B (1 barrier per 6 iters; prefetch issued ~1300cyc before its drain), 10 real
// p-tiles, launch_bounds(256,2) (196 regs, no spill -- r15's (256,3) spilled acc).
// Single bf16-product corr (near-tie flips only; sim err <2e-4); (63,63) exact.

typedef float f32x16 __attribute__((ext_vector_type(16)));
typedef short short8 __attribute__((ext_vector_type(8)));

// ws layout (float words)
#define SATT_H 0u          // bf16 [m][4 cc][1600 pix][16 c] = 3,276,800 f
#define GRDT_H 3276800u    // bf16 [cc=4][ij=576][n=64][16 c] = 1,179,648 f
#define CORR_O 4456448u    // f32 [m][304][64] = 1,245,184 f
#define WIN2_O 5701632u    // f32 [m][289] -> 18,496 f
#define GN2_O  5720128u    // f32 [64]
#define IDX_O  5720192u    // int [4096] (1024 f)
#define CEX_O  5721216u    // f32 [289]

// ---------- T1: satT bf16 [m][cc][pix][16c]. grid 2560 = (m, r); block 256 ----------
__global__ __launch_bounds__(256) void make_satT(const float* __restrict__ sat,
                                                 __hip_bfloat16* __restrict__ sth) {
    __shared__ __hip_bfloat16 th[40 * 66];
    int m = blockIdx.x / 40, r = blockIdx.x % 40;
    int tid = threadIdx.x;
    const float* base = sat + (size_t)m * 262144 + (12 + r) * 64 + 12;
    for (int k = 0; k < 10; k++) {
        int idx = tid + 256 * k;          // 2560 = 64c * 40w
        int c = idx / 40, w2 = idx % 40;
        th[w2 * 66 + c] = __float2bfloat16(base[c * 4096 + w2]);
    }
    __syncthreads();
    __hip_bfloat16* dh = sth + (size_t)m * 102400;
    for (int k = 0; k < 10; k++) {
        int idx = tid + 256 * k;          // idx = w*64 + c
        int w2 = idx >> 6, c = idx & 63;
        dh[(c >> 4) * 25600 + (r * 40 + w2) * 16 + (c & 15)] = th[w2 * 66 + c];
    }
}

// ---------- T2: grdT bf16 [cc][ij][n][16c] + gn2. grid 128 = (n, c-half) ----------
__global__ __launch_bounds__(256) void make_grdT(const float* __restrict__ grd,
                                                 __hip_bfloat16* __restrict__ gth,
                                                 float* __restrict__ gn2) {
    __shared__ __hip_bfloat16 t[32 * 577];
    __shared__ float red[4];
    int bid = blockIdx.x;
    int n = bid >> 1, ch = bid & 1;
    int tid = threadIdx.x;
    const float* src = grd + (size_t)n * 36864 + ch * 32 * 576;
    float s = 0.0f;
    for (int k = 0; k < 72; k++) {
        int idx = tid + 256 * k;          // idx = cl*576 + ij
        int cl = idx / 576, ij = idx % 576;
        float v = src[idx];
        s += v * v;
        t[cl * 577 + ij] = __float2bfloat16(v);
    }
    for (int off = 32; off; off >>= 1) s += __shfl_down(s, off);
    if ((tid & 63) == 0) red[tid >> 6] = s;
    __syncthreads();
    if (tid == 0) atomicAdd(&gn2[n], red[0] + red[1] + red[2] + red[3]);
    for (int k = 0; k < 72; k++) {
        int idx = tid + 256 * k;          // idx = ij*32 + cl
        int ij = idx >> 5, cl = idx & 31;
        int c = ch * 32 + cl;
        gth[((size_t)((c >> 4) * 576 + ij)) * 1024 + n * 16 + (c & 15)] = t[cl * 577 + ij];
    }
}

// ---------- N1: window norms^2 from satT (bf16; rel err ~2e-5). grid 64 (m) ----------
__global__ __launch_bounds__(256) void make_win2(const __hip_bfloat16* __restrict__ sth,
                                                 float* __restrict__ win2) {
    __shared__ float S2[40][41];
    __shared__ float RS[40][18];
    int m = blockIdx.x, tid = threadIdx.x;
    const __hip_bfloat16* base = sth + (size_t)m * 102400;
    for (int k = 0; k < 7; k++) {
        int pix = tid + 256 * k;
        if (pix < 1600) {
            float s = 0.0f;
            for (int cc = 0; cc < 4; cc++) {
                const __hip_bfloat16* p = base + cc * 25600 + pix * 16;
                for (int cl = 0; cl < 16; cl++) {
                    float v = __bfloat162float(p[cl]);
                    s += v * v;
                }
            }
            S2[pix / 40][pix % 40] = s;
        }
    }
    __syncthreads();
    for (int k = 0; k < 3; k++) {
        int idx = tid + 256 * k;
        if (idx < 680) {
            int r = idx / 17, x = idx % 17;
            float s = 0.0f;
            for (int j = 0; j < 24; j++) s += S2[r][x + j];
            RS[r][x] = s;
        }
    }
    __syncthreads();
    for (int k = 0; k < 2; k++) {
        int idx = tid + 256 * k;
        if (idx < 289) {
            int y = idx / 17, x = idx % 17;
            float s = 0.0f;
            for (int i2 = 0; i2 < 24; i2++) s += RS[y + i2][x];
            win2[m * 289 + idx] = s;
        }
    }
}

// ---------- K1: MFMA corr (32x32x16, cc16, G=6 group pipeline). grid 512 ----------
// Block = (m, iq of 3 i-rows). satW = 19 rows x 40 cols x 16c = 24,320 B linear.
// Bl = 2 bufs x 6 ij-planes x [64n][16c] (2 x 12,288 B). Waves 0-1: p-tiles
// {w,w+4,w+8}; waves 2-3: {w,w+4} (10 real tiles; tail clamps, stores guarded).
// Per group: write next-group Bl from regs, issue group+2 loads, 6 compute iters
// {2 B-frag + 3(2) A-frag b128 reads, 6(4) MFMA}, ONE barrier. All LDS linear:
// B-frag reads tile a contiguous 1KB; A-frag reads are 2 contiguous pixel runs.
__global__ __launch_bounds__(256, 2) void corr_mfma(const __hip_bfloat16* __restrict__ sth,
                                                    const __hip_bfloat16* __restrict__ gth,
                                                    float* __restrict__ corr) {
    __shared__ __align__(16) __hip_bfloat16 satW[760 * 16];     // 24,320 B
    __shared__ __align__(16) __hip_bfloat16 Bl[2][6][64 * 16];  // 2 x 12,288 B

    int bid = blockIdx.x;
    int xcd = bid & 7, slot = bid >> 3;             // XCD-aware: 8 m per XCD
    int m = xcd * 8 + (slot >> 3), iq = slot & 7;   // 8 i-slices of 3 rows per m
    int tid = threadIdx.x;
    int w = tid >> 6, l = tid & 63;
    int ln31 = l & 31, h = l >> 5;

    int rowbase[3];
#pragma unroll
    for (int t = 0; t < 3; t++) {
        int p = (w + 4 * t) * 32 + ln31;
        if (p > 288) p = 288;                       // tail rows clamp to a valid pixel
        rowbase[t] = (p / 17) * 40 + (p % 17);
    }
    f32x16 acc[3][2];
#pragma unroll
    for (int t = 0; t < 3; t++) {
        acc[t][0] = (f32x16)0.0f;
        acc[t][1] = (f32x16)0.0f;
    }

    int glb = tid >> 7;            // B-slot plane parity (0/1)
    int wi  = tid & 127;           // 16-B slot within a 2KB ij-plane

    // Load 3 B-planes-worth (ij = 6g+glb, +2, +4) for group G of chunk CC.
#define BLOAD(d0, d1, d2, CC, G) {                                              \
        size_t pb = ((size_t)(CC) * 576 + iq * 72 + 6 * (G) + glb) * 1024 + wi * 8; \
        d0 = *(const float4*)(gth + pb);                                        \
        d1 = *(const float4*)(gth + pb + 2048);                                 \
        d2 = *(const float4*)(gth + pb + 4096);                                 \
    }
#define BWRITE(BUF, v0, v1, v2) {                                               \
        char* bb = (char*)&Bl[BUF][0][0] + glb * 2048 + wi * 16;                \
        *(float4*)bb = v0;                                                      \
        *(float4*)(bb + 4096) = v1;                                             \
        *(float4*)(bb + 8192) = v2;                                             \
    }

#pragma unroll
    for (int cc = 0; cc < 4; cc++) {
        __syncthreads();                            // prior cc's satW/Bl reads done
        // stage satW: 1520 linear 16-B slots from relaid satT
        const __hip_bfloat16* satb = sth + (size_t)m * 102400 + cc * 25600 + iq * 1920;
#pragma unroll
        for (int k2 = 0; k2 < 6; k2++) {
            int s = tid + 256 * k2;
            if (s < 1520) {
                float4 v = *(const float4*)(satb + s * 8);
                *(float4*)((char*)satW + s * 16) = v;
            }
        }
        float4 b0, b1, b2;
        BLOAD(b0, b1, b2, cc, 0);
        BWRITE(0, b0, b1, b2);
        BLOAD(b0, b1, b2, cc, 1);
        __syncthreads();                            // publish satW + Bl[0]

        for (int g = 0; g < 12; g++) {
            int buf = g & 1;
            if (g + 1 < 12) {
                BWRITE(buf ^ 1, b0, b1, b2);
                if (g + 2 < 12) BLOAD(b0, b1, b2, cc, g + 2);
            }
#pragma unroll
            for (int ii = 0; ii < 6; ii++) {
                int ijl = 6 * g + ii;
                int il = ijl / 24;
                int pixoff = il * 40 + (ijl - il * 24);
                const char* blp = (const char*)&Bl[buf][ii][0];
                short8 bf0 = *(const short8*)(blp + ln31 * 32 + h * 16);
                short8 bf1 = *(const short8*)(blp + 1024 + ln31 * 32 + h * 16);
                if (w < 2) {
#pragma unroll
                    for (int t = 0; t < 3; t++) {
                        int ao = (rowbase[t] + pixoff) * 32 + h * 16;
                        short8 af = *(const short8*)((const char*)satW + ao);
                        acc[t][0] = __builtin_amdgcn_mfma_f32_32x32x16_bf16(af, bf0, acc[t][0], 0, 0, 0);
                        acc[t][1] = __builtin_amdgcn_mfma_f32_32x32x16_bf16(af, bf1, acc[t][1], 0, 0, 0);
                    }
                } else {
#pragma unroll
                    for (int t = 0; t < 2; t++) {
                        int ao = (rowbase[t] + pixoff) * 32 + h * 16;
                        short8 af = *(const short8*)((const char*)satW + ao);
                        acc[t][0] = __builtin_amdgcn_mfma_f32_32x32x16_bf16(af, bf0, acc[t][0], 0, 0, 0);
                        acc[t][1] = __builtin_amdgcn_mfma_f32_32x32x16_bf16(af, bf1, acc[t][1], 0, 0, 0);
                    }
                }
            }
            __syncthreads();                        // group boundary (drains g+2 loads,
        }                                           // issued ~6 iters earlier)
    }

    int T = (w < 2) ? 3 : 2;
#pragma unroll
    for (int t = 0; t < 3; t++) {
        if (t >= T) break;
        int tile = w + 4 * t;
#pragma unroll
        for (int nt = 0; nt < 2; nt++)
#pragma unroll
            for (int q = 0; q < 16; q++) {
                int prow = tile * 32 + (q & 3) + 8 * (q >> 2) + 4 * h;
                if (prow < 289)
                    atomicAdd(&corr[((size_t)m * 304 + prow) * 64 + nt * 32 + ln31],
                              acc[t][nt][q]);
            }
    }
#undef BLOAD
#undef BWRITE
}

// ---------- K2: argmax + similarity. grid 4096 = (m,n); block 64 ----------
__global__ __launch_bounds__(64) void argsim(const float* __restrict__ corr,
                                             const float* __restrict__ win2,
                                             const float* __restrict__ gn2,
                                             float* __restrict__ out,
                                             int* __restrict__ idxb) {
    int b = blockIdx.x, m = b >> 6, n = b & 63, lane = threadIdx.x;
    float bv = -3.0e38f;
    int bi = 1 << 30;
    for (int k = 0; k < 5; k++) {
        int p = lane + 64 * k;
        if (p < 289) {
            float v = corr[((size_t)m * 304 + p) * 64 + n];
            if (v > bv) { bv = v; bi = p; }   // ascending p: strict > = first occurrence
        }
    }
    for (int off = 32; off; off >>= 1) {
        float ov = __shfl_down(bv, off);
        int oi = __shfl_down(bi, off);
        if (ov > bv || (ov == bv && oi < bi)) { bv = ov; bi = oi; }
    }
    if (lane == 0) {
        float np = sqrtf(win2[m * 289 + bi]);
        float ng = sqrtf(gn2[n]);
        out[b] = bv / (fmaxf(np, 1e-12f) * fmaxf(ng, 1e-12f));
        idxb[b] = bi;
    }
}

// ---------- K3a: exact fp32 corr for (m,n)=(63,63). grid 289; block 256 ----------
__global__ __launch_bounds__(256) void exact63(const float* __restrict__ sat,
                                               const float* __restrict__ grd,
                                               float* __restrict__ correx) {
    int p = blockIdx.x;
    int hy = p / 17, wx = p % 17;
    int tid = threadIdx.x;
    const float* satm = sat + (size_t)63 * 262144;
    const float* grdn = grd + (size_t)63 * 36864;
    float dot = 0.0f;
    for (int e = tid; e < 36864; e += 256) {
        int c = e / 576, rem = e - c * 576;
        int i = rem / 24, j = rem - i * 24;
        dot += satm[c * 4096 + (12 + hy + i) * 64 + 12 + wx + j] * grdn[e];
    }
    for (int off = 32; off; off >>= 1) dot += __shfl_down(dot, off);
    __shared__ float red[4];
    if ((tid & 63) == 0) red[tid >> 6] = dot;
    __syncthreads();
    if (tid == 0) correx[p] = red[0] + red[1] + red[2] + red[3];
}

// ---------- K3b: fix (63,63) from exact values. grid 1; block 64 ----------
__global__ __launch_bounds__(64) void fix63(const float* __restrict__ correx,
                                            const float* __restrict__ win2,
                                            const float* __restrict__ gn2,
                                            float* __restrict__ out,
                                            int* __restrict__ idxb) {
    int lane = threadIdx.x;
    float bv = -3.0e38f;
    int bi = 1 << 30;
    for (int k = 0; k < 5; k++) {
        int p = lane + 64 * k;
        if (p < 289) {
            float v = correx[p];
            if (v > bv) { bv = v; bi = p; }
        }
    }
    for (int off = 32; off; off >>= 1) {
        float ov = __shfl_down(bv, off);
        int oi = __shfl_down(bi, off);
        if (ov > bv || (ov == bv && oi < bi)) { bv = ov; bi = oi; }
    }
    if (lane == 0) {
        out[4095] = bv / (fmaxf(sqrtf(win2[63 * 289 + bi]), 1e-12f) *
                          fmaxf(sqrtf(gn2[63]), 1e-12f));
        idxb[4095] = bi;
    }
}

// ---------- K4: winning patch for (63,63). grid 144; block 256 ----------
__global__ __launch_bounds__(256) void copy_patch(const float* __restrict__ sat,
                                                  const int* __restrict__ idxb,
                                                  float* __restrict__ out) {
    int fidx = idxb[4095];
    int hy = fidx / 17, wx = fidx % 17;
    int e = blockIdx.x * 256 + threadIdx.x;   // < 36864
    int c = e / 576;
    int rem = e - c * 576;
    int rr = rem / 24, col = rem - rr * 24;
    out[4096 + e] = sat[(size_t)(63 * 64 + c) * 4096 + (12 + hy + rr) * 64 + 12 + wx + col];
}

extern "C" void kernel_launch(void* const* d_in, const int* in_sizes, int n_in,
                              void* d_out, int out_size, void* d_ws, size_t ws_size,
                              hipStream_t stream) {
    const float* grd = (const float*)d_in[0];
    const float* sat = (const float*)d_in[1];
    float* out = (float*)d_out;

    float* wsf = (float*)d_ws;
    __hip_bfloat16* sth = (__hip_bfloat16*)(wsf + SATT_H);
    __hip_bfloat16* gth = (__hip_bfloat16*)(wsf + GRDT_H);
    float* corr = wsf + CORR_O;
    float* win2 = wsf + WIN2_O;
    float* gn2  = wsf + GN2_O;
    int*   idxb = (int*)(wsf + IDX_O);
    float* cex  = wsf + CEX_O;

    // one memset covers corr + win2 + gn2 (contiguous): 1,263,744 floats
    hipMemsetAsync(corr, 0, (size_t)1263744 * sizeof(float), stream);
    make_satT<<<2560, 256, 0, stream>>>(sat, sth);
    make_grdT<<<128, 256, 0, stream>>>(grd, gth, gn2);
    make_win2<<<64, 256, 0, stream>>>(sth, win2);
    corr_mfma<<<512, 256, 0, stream>>>(sth, gth, corr);
    argsim<<<4096, 64, 0, stream>>>(corr, win2, gn2, out, idxb);
    exact63<<<289, 256, 0, stream>>>(sat, grd, cex);
    fix63<<<1, 64, 0, stream>>>(cex, win2, gn2, out, idxb);
    copy_patch<<<144, 256, 0, stream>>>(sat, idxb, out);
}

// Round 17
// 192.197 us; speedup vs baseline: 3.4714x; 1.0032x over previous
//
#include <hip/hip_runtime.h>
#include <hip/hip_bf16.h>
#include <math.h>

// Shapes: grd (N=64,C=64,24,24), sat (M=64,C=64,64,64); crop sat[:,:,12:52,12:52] (40x40)
// corr (64,64,17,17); out: [0,4096) similarity f32, [4096,40960) sat_f (64,24,24) f32.
//
// Round-17: B operands bypass LDS entirely. Round-16 counters: conflicts track b128
// instruction count (minimum aliasing), and 4 waves read IDENTICAL B frags via LDS
// (4x duplication) -> B-reads+Bl-writes were ~50% of LDS ops. Now each wave loads
// its B frags as wave-contiguous 1KB global reads from the relaid gth (2.25MB,
// L2-resident; L1 absorbs in-block duplication) with a 3-deep rotating register
// prefetch (named x/y/z sets, loop unrolled x3 -> static indexing). LDS = satW only
// (24.3KB); barriers only at the 4 cc boundaries. Unlike round-12's failure this is
// coalesced 1KB reads of a tiny hot array, not per-lane 4096-B-strided scatter.
// Single bf16-product corr (near-tie flips only; sim err <2e-4); (63,63) exact.

typedef float f32x16 __attribute__((ext_vector_type(16)));
typedef short short8 __attribute__((ext_vector_type(8)));

// ws layout (float words)
#define SATT_H 0u          // bf16 [m][4 cc][1600 pix][16 c] = 3,276,800 f
#define GRDT_H 3276800u    // bf16 [cc=4][ij=576][n=64][16 c] = 1,179,648 f
#define CORR_O 4456448u    // f32 [m][304][64] = 1,245,184 f
#define WIN2_O 5701632u    // f32 [m][289] -> 18,496 f
#define GN2_O  5720128u    // f32 [64]
#define IDX_O  5720192u    // int [4096] (1024 f)
#define CEX_O  5721216u    // f32 [289]

// ---------- T1: satT bf16 [m][cc][pix][16c]. grid 2560 = (m, r); block 256 ----------
__global__ __launch_bounds__(256) void make_satT(const float* __restrict__ sat,
                                                 __hip_bfloat16* __restrict__ sth) {
    __shared__ __hip_bfloat16 th[40 * 66];
    int m = blockIdx.x / 40, r = blockIdx.x % 40;
    int tid = threadIdx.x;
    const float* base = sat + (size_t)m * 262144 + (12 + r) * 64 + 12;
    for (int k = 0; k < 10; k++) {
        int idx = tid + 256 * k;          // 2560 = 64c * 40w
        int c = idx / 40, w2 = idx % 40;
        th[w2 * 66 + c] = __float2bfloat16(base[c * 4096 + w2]);
    }
    __syncthreads();
    // dst for this r: 4 contiguous runs of 640 elems (one per cc) -> coalesced
    __hip_bfloat16* dh = sth + (size_t)m * 102400 + r * 640;
    for (int k = 0; k < 10; k++) {
        int idx = tid + 256 * k;          // idx = cc*640 + w2*16 + cl
        int cc = idx / 640, rem = idx - cc * 640;
        int w2 = rem >> 4, cl = rem & 15;
        dh[cc * 25600 + w2 * 16 + cl] = th[w2 * 66 + cc * 16 + cl];
    }
}

// ---------- T2: grdT bf16 [cc][ij][n][16c] + gn2. grid 128 = (n, c-half) ----------
__global__ __launch_bounds__(256) void make_grdT(const float* __restrict__ grd,
                                                 __hip_bfloat16* __restrict__ gth,
                                                 float* __restrict__ gn2) {
    __shared__ __hip_bfloat16 t[32 * 577];
    __shared__ float red[4];
    int bid = blockIdx.x;
    int n = bid >> 1, ch = bid & 1;
    int tid = threadIdx.x;
    const float* src = grd + (size_t)n * 36864 + ch * 32 * 576;
    float s = 0.0f;
    for (int k = 0; k < 72; k++) {
        int idx = tid + 256 * k;          // idx = cl*576 + ij
        int cl = idx / 576, ij = idx % 576;
        float v = src[idx];
        s += v * v;
        t[cl * 577 + ij] = __float2bfloat16(v);
    }
    for (int off = 32; off; off >>= 1) s += __shfl_down(s, off);
    if ((tid & 63) == 0) red[tid >> 6] = s;
    __syncthreads();
    if (tid == 0) atomicAdd(&gn2[n], red[0] + red[1] + red[2] + red[3]);
    for (int k = 0; k < 72; k++) {
        int idx = tid + 256 * k;          // idx = ij*32 + cl
        int ij = idx >> 5, cl = idx & 31;
        int c = ch * 32 + cl;
        gth[((size_t)((c >> 4) * 576 + ij)) * 1024 + n * 16 + (c & 15)] = t[cl * 577 + ij];
    }
}

// ---------- N1: window norms^2 from satT (bf16; rel err ~2e-5). grid 64 (m) ----------
__global__ __launch_bounds__(256) void make_win2(const __hip_bfloat16* __restrict__ sth,
                                                 float* __restrict__ win2) {
    __shared__ float S2[40][41];
    __shared__ float RS[40][18];
    int m = blockIdx.x, tid = threadIdx.x;
    const __hip_bfloat16* base = sth + (size_t)m * 102400;
    for (int k = 0; k < 7; k++) {
        int pix = tid + 256 * k;
        if (pix < 1600) {
            float s = 0.0f;
            for (int cc = 0; cc < 4; cc++) {
                const __hip_bfloat16* p = base + cc * 25600 + pix * 16;
                for (int cl = 0; cl < 16; cl++) {
                    float v = __bfloat162float(p[cl]);
                    s += v * v;
                }
            }
            S2[pix / 40][pix % 40] = s;
        }
    }
    __syncthreads();
    for (int k = 0; k < 3; k++) {
        int idx = tid + 256 * k;
        if (idx < 680) {
            int r = idx / 17, x = idx % 17;
            float s = 0.0f;
            for (int j = 0; j < 24; j++) s += S2[r][x + j];
            RS[r][x] = s;
        }
    }
    __syncthreads();
    for (int k = 0; k < 2; k++) {
        int idx = tid + 256 * k;
        if (idx < 289) {
            int y = idx / 17, x = idx % 17;
            float s = 0.0f;
            for (int i2 = 0; i2 < 24; i2++) s += RS[y + i2][x];
            win2[m * 289 + idx] = s;
        }
    }
}

// ---------- K1: MFMA corr (32x32x16, cc16, B in registers). grid 512 ----------
// Block = (m, iq of 3 i-rows). satW = 19 rows x 40 cols x 16c = 24,320 B linear,
// the ONLY LDS use. Waves 0-1: p-tiles {w,w+4,w+8}; waves 2-3: {w,w+4} (10 real
// tiles; tail clamps, stores guarded). Both n-tiles per wave (acc 3x2 f32x16).
// B: per-wave contiguous 1KB global loads from gth planes, 3-deep rotating
// register prefetch (x/y/z), loop unrolled x3 -> all names static.
__global__ __launch_bounds__(256, 2) void corr_mfma(const __hip_bfloat16* __restrict__ sth,
                                                    const __hip_bfloat16* __restrict__ gth,
                                                    float* __restrict__ corr) {
    __shared__ __align__(16) __hip_bfloat16 satW[760 * 16];     // 24,320 B

    int bid = blockIdx.x;
    int xcd = bid & 7, slot = bid >> 3;             // XCD-aware: 8 m per XCD
    int m = xcd * 8 + (slot >> 3), iq = slot & 7;   // 8 i-slices of 3 rows per m
    int tid = threadIdx.x;
    int w = tid >> 6, l = tid & 63;
    int ln31 = l & 31, h = l >> 5;

    int rowbase[3];
#pragma unroll
    for (int t = 0; t < 3; t++) {
        int p = (w + 4 * t) * 32 + ln31;
        if (p > 288) p = 288;                       // tail rows clamp to a valid pixel
        rowbase[t] = (p / 17) * 40 + (p % 17);
    }
    f32x16 acc[3][2];
#pragma unroll
    for (int t = 0; t < 3; t++) {
        acc[t][0] = (f32x16)0.0f;
        acc[t][1] = (f32x16)0.0f;
    }

    // B per-lane address: plane (cc*576 + iq*72 + ijl) of 1024 elems;
    // lane frag = [n = nt*32 + ln31][c = h*8..h*8+7] -> elem (nt*32+ln31)*16 + h*8.
    const __hip_bfloat16* gbase = gth + (size_t)(iq * 72) * 1024 + ln31 * 16 + h * 8;

#define BLOADR(B0, B1, CC, IJL) {                                               \
        const __hip_bfloat16* p_ = gbase + ((size_t)(CC) * 576 + (IJL)) * 1024; \
        B0 = *(const short8*)p_;                                                \
        B1 = *(const short8*)(p_ + 512);                                        \
    }
#define COMPUTE(IJL, B0, B1) {                                                  \
        int il_ = (IJL) / 24;                                                   \
        int pixoff_ = il_ * 40 + ((IJL) - il_ * 24);                            \
        if (w < 2) {                                                            \
            _Pragma("unroll")                                                   \
            for (int t = 0; t < 3; t++) {                                       \
                int ao = (rowbase[t] + pixoff_) * 32 + h * 16;                  \
                short8 af = *(const short8*)((const char*)satW + ao);           \
                acc[t][0] = __builtin_amdgcn_mfma_f32_32x32x16_bf16(af, B0, acc[t][0], 0, 0, 0); \
                acc[t][1] = __builtin_amdgcn_mfma_f32_32x32x16_bf16(af, B1, acc[t][1], 0, 0, 0); \
            }                                                                   \
        } else {                                                                \
            _Pragma("unroll")                                                   \
            for (int t = 0; t < 2; t++) {                                       \
                int ao = (rowbase[t] + pixoff_) * 32 + h * 16;                  \
                short8 af = *(const short8*)((const char*)satW + ao);           \
                acc[t][0] = __builtin_amdgcn_mfma_f32_32x32x16_bf16(af, B0, acc[t][0], 0, 0, 0); \
                acc[t][1] = __builtin_amdgcn_mfma_f32_32x32x16_bf16(af, B1, acc[t][1], 0, 0, 0); \
            }                                                                   \
        }                                                                       \
    }

#pragma unroll
    for (int cc = 0; cc < 4; cc++) {
        __syncthreads();                            // prior cc's satW reads done
        // stage satW: 1520 linear 16-B slots from relaid satT
        const __hip_bfloat16* satb = sth + (size_t)m * 102400 + cc * 25600 + iq * 1920;
#pragma unroll
        for (int k2 = 0; k2 < 6; k2++) {
            int s = tid + 256 * k2;
            if (s < 1520) {
                float4 v = *(const float4*)(satb + s * 8);
                *(float4*)((char*)satW + s * 16) = v;
            }
        }
        short8 x0, x1, y0, y1, z0, z1;
        BLOADR(x0, x1, cc, 0);
        BLOADR(y0, y1, cc, 1);
        BLOADR(z0, z1, cc, 2);
        __syncthreads();                            // publish satW

        for (int ijg = 0; ijg < 24; ijg++) {
            int base = ijg * 3;
            COMPUTE(base + 0, x0, x1);
            if (base + 3 < 72) BLOADR(x0, x1, cc, base + 3);
            COMPUTE(base + 1, y0, y1);
            if (base + 4 < 72) BLOADR(y0, y1, cc, base + 4);
            COMPUTE(base + 2, z0, z1);
            if (base + 5 < 72) BLOADR(z0, z1, cc, base + 5);
        }
    }

    int T = (w < 2) ? 3 : 2;
#pragma unroll
    for (int t = 0; t < 3; t++) {
        if (t >= T) break;
        int tile = w + 4 * t;
#pragma unroll
        for (int nt = 0; nt < 2; nt++)
#pragma unroll
            for (int q = 0; q < 16; q++) {
                int prow = tile * 32 + (q & 3) + 8 * (q >> 2) + 4 * h;
                if (prow < 289)
                    atomicAdd(&corr[((size_t)m * 304 + prow) * 64 + nt * 32 + ln31],
                              acc[t][nt][q]);
            }
    }
#undef BLOADR
#undef COMPUTE
}

// ---------- K2: argmax + similarity. grid 4096 = (m,n); block 64 ----------
__global__ __launch_bounds__(64) void argsim(const float* __restrict__ corr,
                                             const float* __restrict__ win2,
                                             const float* __restrict__ gn2,
                                             float* __restrict__ out,
                                             int* __restrict__ idxb) {
    int b = blockIdx.x, m = b >> 6, n = b & 63, lane = threadIdx.x;
    float bv = -3.0e38f;
    int bi = 1 << 30;
    for (int k = 0; k < 5; k++) {
        int p = lane + 64 * k;
        if (p < 289) {
            float v = corr[((size_t)m * 304 + p) * 64 + n];
            if (v > bv) { bv = v; bi = p; }   // ascending p: strict > = first occurrence
        }
    }
    for (int off = 32; off; off >>= 1) {
        float ov = __shfl_down(bv, off);
        int oi = __shfl_down(bi, off);
        if (ov > bv || (ov == bv && oi < bi)) { bv = ov; bi = oi; }
    }
    if (lane == 0) {
        float np = sqrtf(win2[m * 289 + bi]);
        float ng = sqrtf(gn2[n]);
        out[b] = bv / (fmaxf(np, 1e-12f) * fmaxf(ng, 1e-12f));
        idxb[b] = bi;
    }
}

// ---------- K3a: exact fp32 corr for (m,n)=(63,63). grid 289; block 256 ----------
__global__ __launch_bounds__(256) void exact63(const float* __restrict__ sat,
                                               const float* __restrict__ grd,
                                               float* __restrict__ correx) {
    int p = blockIdx.x;
    int hy = p / 17, wx = p % 17;
    int tid = threadIdx.x;
    const float* satm = sat + (size_t)63 * 262144;
    const float* grdn = grd + (size_t)63 * 36864;
    float dot = 0.0f;
    for (int e = tid; e < 36864; e += 256) {
        int c = e / 576, rem = e - c * 576;
        int i = rem / 24, j = rem - i * 24;
        dot += satm[c * 4096 + (12 + hy + i) * 64 + 12 + wx + j] * grdn[e];
    }
    for (int off = 32; off; off >>= 1) dot += __shfl_down(dot, off);
    __shared__ float red[4];
    if ((tid & 63) == 0) red[tid >> 6] = dot;
    __syncthreads();
    if (tid == 0) correx[p] = red[0] + red[1] + red[2] + red[3];
}

// ---------- K3b: fix (63,63) from exact values. grid 1; block 64 ----------
__global__ __launch_bounds__(64) void fix63(const float* __restrict__ correx,
                                            const float* __restrict__ win2,
                                            const float* __restrict__ gn2,
                                            float* __restrict__ out,
                                            int* __restrict__ idxb) {
    int lane = threadIdx.x;
    float bv = -3.0e38f;
    int bi = 1 << 30;
    for (int k = 0; k < 5; k++) {
        int p = lane + 64 * k;
        if (p < 289) {
            float v = correx[p];
            if (v > bv) { bv = v; bi = p; }
        }
    }
    for (int off = 32; off; off >>= 1) {
        float ov = __shfl_down(bv, off);
        int oi = __shfl_down(bi, off);
        if (ov > bv || (ov == bv && oi < bi)) { bv = ov; bi = oi; }
    }
    if (lane == 0) {
        out[4095] = bv / (fmaxf(sqrtf(win2[63 * 289 + bi]), 1e-12f) *
                          fmaxf(sqrtf(gn2[63]), 1e-12f));
        idxb[4095] = bi;
    }
}

// ---------- K4: winning patch for (63,63). grid 144; block 256 ----------
__global__ __launch_bounds__(256) void copy_patch(const float* __restrict__ sat,
                                                  const int* __restrict__ idxb,
                                                  float* __restrict__ out) {
    int fidx = idxb[4095];
    int hy = fidx / 17, wx = fidx % 17;
    int e = blockIdx.x * 256 + threadIdx.x;   // < 36864
    int c = e / 576;
    int rem = e - c * 576;
    int rr = rem / 24, col = rem - rr * 24;
    out[4096 + e] = sat[(size_t)(63 * 64 + c) * 4096 + (12 + hy + rr) * 64 + 12 + wx + col];
}

extern "C" void kernel_launch(void* const* d_in, const int* in_sizes, int n_in,
                              void* d_out, int out_size, void* d_ws, size_t ws_size,
                              hipStream_t stream) {
    const float* grd = (const float*)d_in[0];
    const float* sat = (const float*)d_in[1];
    float* out = (float*)d_out;

    float* wsf = (float*)d_ws;
    __hip_bfloat16* sth = (__hip_bfloat16*)(wsf + SATT_H);
    __hip_bfloat16* gth = (__hip_bfloat16*)(wsf + GRDT_H);
    float* corr = wsf + CORR_O;
    float* win2 = wsf + WIN2_O;
    float* gn2  = wsf + GN2_O;
    int*   idxb = (int*)(wsf + IDX_O);
    float* cex  = wsf + CEX_O;

    // one memset covers corr + win2 + gn2 (contiguous): 1,263,744 floats
    hipMemsetAsync(corr, 0, (size_t)1263744 * sizeof(float), stream);
    make_satT<<<2560, 256, 0, stream>>>(sat, sth);
    make_grdT<<<128, 256, 0, stream>>>(grd, gth, gn2);
    make_win2<<<64, 256, 0, stream>>>(sth, win2);
    corr_mfma<<<512, 256, 0, stream>>>(sth, gth, corr);
    argsim<<<4096, 64, 0, stream>>>(corr, win2, gn2, out, idxb);
    exact63<<<289, 256, 0, stream>>>(sat, grd, cex);
    fix63<<<1, 64, 0, stream>>>(cex, win2, gn2, out, idxb);
    copy_patch<<<144, 256, 0, stream>>>(sat, idxb, out);
}